// Round 8
// baseline (961.256 us; speedup 1.0000x reference)
//
#include <hip/hip_runtime.h>
#include <hip/hip_fp16.h>

typedef _Float16 f16;
typedef _Float16 f16x2 __attribute__((ext_vector_type(2)));
typedef _Float16 f16x8 __attribute__((ext_vector_type(8)));
typedef float    f32x4 __attribute__((ext_vector_type(4)));

#define NB   8192
#define TOUT 10
#define LMAX 12
#define EMB  300

__device__ __forceinline__ float sigm_(float x) {
    return __builtin_amdgcn_rcpf(1.0f + __builtin_amdgcn_exp2f(x * -1.44269504f));
}
__device__ __forceinline__ float tanh_(float x) {
    return 1.0f - 2.0f * __builtin_amdgcn_rcpf(1.0f + __builtin_amdgcn_exp2f(x * 2.88539008f));
}
__device__ __forceinline__ f16x2 pk_f16(float a, float b) {
    return __builtin_bit_cast(f16x2, __builtin_amdgcn_cvt_pkrtz(a, b));
}

// async global->LDS, 16B per lane. LDS dest is wave-uniform base + lane*16.
// Round-5 lesson: use ONLY for true HBM/L3 streams (seq), never weights.
__device__ __forceinline__ void gl_lds16(const f16* g, f16* l) {
    __builtin_amdgcn_global_load_lds(
        (const __attribute__((address_space(1))) void*)g,
        (__attribute__((address_space(3))) void*)l, 16, 0, 0);
}

#define MF(a, b, c) __builtin_amdgcn_mfma_f32_16x16x32_f16(a, b, c, 0, 0, 0)

// ---------------------------------------------------------------------------
// K0a: pack LSTM weights into MFMA B-fragment tiles, f16, gate-permuted cols.
// Dest per dir: [kc 0..15][ntile 0..63][512 f16]; within tile element (k,n):
// offset = ((k%32)/8*16 + n%16)*8 + k%8 (lane l reads l*8..l*8+7).
// Column permutation (8-wave / 128-col-per-wave, round-0 scheme):
//   n -> w=n/128, rr=n%128, gate=rr>>5, us=(rr>>4)&1, l16=rr&15,
//   unit u = w*32 + 2*l16 + us;  srow = gate*256 + u.
// Wave's 8 n-tiles = 4 gates x 2 unit-subtiles; lane l16 owns units
// (2*l16, 2*l16+1) -> f16x2 h stores in the combine.
// ---------------------------------------------------------------------------
__global__ __launch_bounds__(256) void pack_w2(
    const float* __restrict__ wih_f, const float* __restrict__ whh_f,
    const float* __restrict__ wih_b, const float* __restrict__ whh_b,
    f16* __restrict__ Wp) {
    int idx = blockIdx.x * 256 + threadIdx.x;   // 0 .. 2*524288-1
    int d   = idx >> 19;
    int r   = idx & 524287;
    int tile = r >> 9;
    int e    = r & 511;
    int kc = tile >> 6, nt = tile & 63;
    int khi = e >> 7, rem = e & 127, nl = rem >> 3, klo = rem & 7;
    int n = nt * 16 + nl;
    int k = kc * 32 + khi * 8 + klo;
    int w = n >> 7, rr = n & 127, gate = rr >> 5;
    int u = w * 32 + 2 * (rr & 15) + ((rr >> 4) & 1);
    int srow = gate * 256 + u;
    const float* wih = d ? wih_b : wih_f;
    const float* whh = d ? whh_b : whh_f;
    float v = (k < 256) ? wih[srow * 256 + k] : whh[srow * 256 + (k - 256)];
    Wp[idx] = (f16)v;
}

__global__ __launch_bounds__(256) void pack_bias(
    const float* __restrict__ bih_f, const float* __restrict__ bhh_f,
    const float* __restrict__ bih_b, const float* __restrict__ bhh_b,
    float* __restrict__ bp) {
    int idx = blockIdx.x * 256 + threadIdx.x;   // 2048
    int d = idx >> 10, n = idx & 1023;
    int w = n >> 7, rr = n & 127, gate = rr >> 5;
    int u = w * 32 + 2 * (rr & 15) + ((rr >> 4) & 1);
    int srow = gate * 256 + u;
    bp[idx] = d ? (bih_b[srow] + bhh_b[srow]) : (bih_f[srow] + bhh_f[srow]);
}

// K0b: pack out_w (512x512) into B-fragment tiles: [kc 0..15][ntile 0..31][512]
__global__ __launch_bounds__(256) void pack_w3(
    const float* __restrict__ out_w, f16* __restrict__ W3p) {
    int idx = blockIdx.x * 256 + threadIdx.x;   // 262144
    int tile = idx >> 9, e = idx & 511;
    int kc = tile >> 5, nt = tile & 31;
    int khi = e >> 7, rem = e & 127, nl = rem >> 3, klo = rem & 7;
    int n = nt * 16 + nl, k = kc * 32 + khi * 8 + klo;
    W3p[idx] = (f16)out_w[n * 512 + k];
}

// K0c: P[36][256] = emb_table @ enc_w^T + enc_b (fp32)
__global__ __launch_bounds__(256) void enc_proj(
    const float* __restrict__ tab, const float* __restrict__ ew,
    const float* __restrict__ eb, float* __restrict__ P) {
    int v = blockIdx.x, j = threadIdx.x;
    const float* a = tab + v * EMB;
    const float* w = ew + j * EMB;
    float s = 0.0f;
    for (int k = 0; k < EMB; ++k) s += a[k] * w[k];
    P[v * 256 + j] = s + eb[j];
}

// ---------------------------------------------------------------------------
// K1: build seq in MFMA A-fragment tile layout, f16.
// seqp: [t 0..9][mtile 0..511][kc 0..7][512 f16]; element (row,k):
// offset = ((k%32)/8*16 + row%16)*8 + k%8
// ---------------------------------------------------------------------------
__global__ __launch_bounds__(256) void build_seq(
    const int* __restrict__ words, const int* __restrict__ lengths,
    const float* __restrict__ P, f16* __restrict__ seqp) {
    int gi = blockIdx.x * 256 + threadIdx.x;    // 2,621,440 total
    int bl  = gi & 15;
    int khi = (gi >> 4) & 3;
    int kc  = (gi >> 6) & 7;
    int mt  = (gi >> 9) & 511;
    int t   = gi >> 18;
    int b = mt * 16 + bl;
    int L = lengths[b];
    float pos = ((float)t * (float)(L - 1)) / 9.0f;
    int i0 = (int)pos;
    float f = pos - (float)i0;
    int i1 = min(i0 + 1, L - 1);
    int c0 = words[b * LMAX + i0];
    int c1 = words[b * LMAX + i1];
    const float* p0 = P + c0 * 256 + kc * 32 + khi * 8;
    const float* p1 = P + c1 * 256 + kc * 32 + khi * 8;
    f16x8 r;
#pragma unroll
    for (int j = 0; j < 8; ++j) {
        float v = p0[j] * (1.0f - f) + p1[j] * f;
        v = fmaxf(v, 0.0f);
        r[j] = (f16)v;
    }
    *((f16x8*)seqp + gi) = r;
}

// ---------------------------------------------------------------------------
// K2: fused BiLSTM. 256 blocks (128 fwd + 128 bwd) x 512 thr (8 waves),
// 1 block/CU, 2 waves/SIMD, 256 reg/lane budget.
// Round-7/8 pipeline (round-7 bench was an infra failure, resubmitted):
//  - 3-set weight rotation S0/S1/S2 (4 tiles = 16 VGPR each): half-phase p
//    consumes S[p%3] while S[(p+2)%3]'s 4 loads fly, issued 2 phases
//    (~620 cy of MFMA) ahead of use -> counted vmcnt(8), never a drain.
//  - seq gl_lds DMA issued at the FIFO TAIL (after the last weight load);
//    only the step-end barrier drains it (fixes round-4's issue-order bug:
//    vmcnt retires in issue order, so a head-of-FIFO seq DMA forced every
//    counted weight-wait to transitively drain 32KB of HBM traffic).
//  - cross-step prefetch: next step's S0/S1 (weights are step-invariant)
//    issued before the combine -> they land during combine+barrier, so the
//    next step starts MFMA with zero prologue stall.
// LDS = hbuf dbuf 64 KB + sbuf dbuf 64 KB. One barrier per step.
// ---------------------------------------------------------------------------
__global__ __launch_bounds__(512) void lstm_fused(
    const f16* __restrict__ seqp, const f16* __restrict__ Wp,
    const float* __restrict__ bp, f16* __restrict__ hcat) {
    const int dir  = blockIdx.x >> 7;
    const int r0t  = (blockIdx.x & 127) << 2;   // row-tile base, 4 tiles of 16
    const int wave = threadIdx.x >> 6;          // 0..7
    const int lane = threadIdx.x & 63;
    const int l16  = lane & 15;
    const int quad = lane >> 4;

    __shared__ __align__(16) f16 hbuf[2][16384];   // 2 x 32 KB  h state
    __shared__ __align__(16) f16 sbuf[2][16384];   // 2 x 32 KB  seq tiles

    // zero h0 buffer
    {
        f16x8 z = {(f16)0, (f16)0, (f16)0, (f16)0, (f16)0, (f16)0, (f16)0, (f16)0};
        for (int i = threadIdx.x; i < 2048; i += 512) ((f16x8*)hbuf[0])[i] = z;
    }
    // stage seq tile for t0 into sbuf[0]
    {
        const int t0 = dir ? 9 : 0;
        const f16* s0 = seqp + (size_t)(t0 * 512 + r0t) * 4096;
#pragma unroll
        for (int r = 0; r < 4; ++r)
            gl_lds16(s0 + r * 4096 + threadIdx.x * 8, &sbuf[0][r * 4096 + wave * 512]);
    }

    // per-lane gate biases: wave owns cols [wave*128, wave*128+128)
    const float* bpd = bp + dir * 1024 + wave * 128;
    float bias_l[8];
#pragma unroll
    for (int nt = 0; nt < 8; ++nt) bias_l[nt] = bpd[nt * 16 + l16];

    // weight tile (kc, nt) at Wdl + kc*32768 + nt*512
    const f16* Wdl = Wp + dir * 524288 + wave * 4096 + lane * 8;

    // combine geometry (round-0): lane owns units 2*l16, 2*l16+1
    const int wt0 = ((l16 >> 2) * 16 + quad * 4) * 8 + 2 * (l16 & 3);
    const int tile_lo = (r0t * 16 + dir * 8 + wave) * 512;

    float cst[4][4][2];
#pragma unroll
    for (int m = 0; m < 4; ++m)
#pragma unroll
        for (int q = 0; q < 4; ++q) { cst[m][q][0] = 0.0f; cst[m][q][1] = 0.0f; }

    // initial weight prologue: S0 <- (kc8, nt0..3), S1 <- (kc8, nt4..7)
    f16x8 S0[4], S1[4], S2[4];
#pragma unroll
    for (int nt = 0; nt < 4; ++nt) S0[nt] = *(const f16x8*)(Wdl + 8 * 32768 + nt * 512);
#pragma unroll
    for (int nt = 0; nt < 4; ++nt) S1[nt] = *(const f16x8*)(Wdl + 8 * 32768 + (4 + nt) * 512);

    __syncthreads();   // drains h0 zero + t0 seq DMA (prologue regs land too)

// half-phase P (0..31): kc = (P>>1)^8 (h-half first), tiles = (P&1)*4 + 0..3.
// SC = consume set, SD = dest set for phase P+2.
#define HSTEP(P, SC, SD) do {                                                  \
    if ((P) < 30) {                                                            \
        const f16* ws_ = Wdl + (((((P) + 2) >> 1) ^ 8) * 32768                 \
                                + (((P) + 2) & 1) * 2048);                     \
        _Pragma("unroll")                                                      \
        for (int nt_ = 0; nt_ < 4; ++nt_)                                      \
            SD[nt_] = *(const f16x8*)(ws_ + nt_ * 512);                        \
    }                                                                          \
    if (((P) & 1) == 0) {                                                      \
        const f16* ab_ = ((P) < 16) ? hb_r : sb;                               \
        const int c_ = ((P) >> 1) & 7;                                         \
        _Pragma("unroll")                                                      \
        for (int m_ = 0; m_ < 4; ++m_)                                         \
            aA[m_] = *(const f16x8*)(ab_ + (m_ * 8 + c_) * 512);               \
    }                                                                          \
    __builtin_amdgcn_s_setprio(1);                                             \
    _Pragma("unroll")                                                          \
    for (int m_ = 0; m_ < 4; ++m_) {                                           \
        _Pragma("unroll")                                                      \
        for (int nt_ = 0; nt_ < 4; ++nt_)                                      \
            acc[m_][((P) & 1) * 4 + nt_] =                                     \
                MF(aA[m_], SC[nt_], acc[m_][((P) & 1) * 4 + nt_]);             \
    }                                                                          \
    __builtin_amdgcn_s_setprio(0);                                             \
} while (0)

    int cur = 0;
#pragma unroll 1
    for (int step = 0; step < TOUT; ++step) {
        const int t = dir ? (9 - step) : step;
        const f16* hb_r = hbuf[cur] + lane * 8;
        const f16* sb   = sbuf[cur] + lane * 8;
        f16*       hb_w = hbuf[cur ^ 1];

        f32x4 acc[4][8];
#pragma unroll
        for (int m = 0; m < 4; ++m)
#pragma unroll
            for (int nt = 0; nt < 8; ++nt)
#pragma unroll
                for (int q = 0; q < 4; ++q) acc[m][nt][q] = bias_l[nt];

        f16x8 aA[4];

        // 32 half-phases; rotation pattern (consume, dest) has period 3:
        // (S0,S2) (S1,S0) (S2,S1) ...
        HSTEP(0, S0, S2);  HSTEP(1, S1, S0);  HSTEP(2, S2, S1);
        HSTEP(3, S0, S2);  HSTEP(4, S1, S0);  HSTEP(5, S2, S1);
        HSTEP(6, S0, S2);  HSTEP(7, S1, S0);  HSTEP(8, S2, S1);
        HSTEP(9, S0, S2);  HSTEP(10, S1, S0); HSTEP(11, S2, S1);
        HSTEP(12, S0, S2); HSTEP(13, S1, S0); HSTEP(14, S2, S1);
        HSTEP(15, S0, S2); HSTEP(16, S1, S0); HSTEP(17, S2, S1);
        HSTEP(18, S0, S2); HSTEP(19, S1, S0); HSTEP(20, S2, S1);
        HSTEP(21, S0, S2); HSTEP(22, S1, S0); HSTEP(23, S2, S1);
        HSTEP(24, S0, S2); HSTEP(25, S1, S0); HSTEP(26, S2, S1);
        HSTEP(27, S0, S2); HSTEP(28, S1, S0); HSTEP(29, S2, S1);
        HSTEP(30, S0, S2); HSTEP(31, S1, S0);

        // cross-step weight prefetch (same addresses every step): lands
        // during combine + barrier -> next step starts with zero stall.
#pragma unroll
        for (int nt = 0; nt < 4; ++nt) S0[nt] = *(const f16x8*)(Wdl + 8 * 32768 + nt * 512);
#pragma unroll
        for (int nt = 0; nt < 4; ++nt) S1[nt] = *(const f16x8*)(Wdl + 8 * 32768 + (4 + nt) * 512);

        // seq prefetch for next step: FIFO TAIL (younger than every weight
        // load), drained only by the step-end barrier.
        if (step != 9) {
            const int tn = dir ? (t - 1) : (t + 1);
            const f16* ns = seqp + (size_t)(tn * 512 + r0t) * 4096;
#pragma unroll
            for (int r = 0; r < 4; ++r)
                gl_lds16(ns + r * 4096 + threadIdx.x * 8,
                         &sbuf[cur ^ 1][r * 4096 + wave * 512]);
        }

        // lane-local gate combine; h -> LDS (recurrence) + global hcat.
        // acc[m][nt][q]: row = m*16+quad*4+q; nt = gate*2+us; units 2*l16+us
        f16* hct = hcat + ((size_t)t * 4194304 + tile_lo);
#pragma unroll
        for (int m = 0; m < 4; ++m) {
#pragma unroll
            for (int q = 0; q < 4; ++q) {
                float i0 = acc[m][0][q], i1 = acc[m][1][q];
                float f0 = acc[m][2][q], f1 = acc[m][3][q];
                float g0 = acc[m][4][q], g1 = acc[m][5][q];
                float o0 = acc[m][6][q], o1 = acc[m][7][q];
                float c0 = sigm_(f0) * cst[m][q][0] + sigm_(i0) * tanh_(g0);
                float c1 = sigm_(f1) * cst[m][q][1] + sigm_(i1) * tanh_(g1);
                cst[m][q][0] = c0;
                cst[m][q][1] = c1;
                float h0 = sigm_(o0) * tanh_(c0);
                float h1 = sigm_(o1) * tanh_(c1);
                f16x2 hv = pk_f16(h0, h1);
                int wt = wt0 + q * 8;
                *(f16x2*)&hb_w[(m * 8 + wave) * 512 + wt] = hv;
                *(f16x2*)(hct + m * 8192 + wt) = hv;
            }
        }

        __syncthreads();   // single barrier per step; drains seq DMA + stores
        cur ^= 1;
    }
#undef HSTEP
}

// ---------------------------------------------------------------------------
// K3: out = h_cat(81920x512 f16, frag layout) @ W3p + out_b -> fp32 (B,10,512)
// 1280 blocks x 512 thr; block tile 64 rows x 512 cols; wave: 64x64.
// ---------------------------------------------------------------------------
__global__ __launch_bounds__(512) void out_gemm(
    const f16* __restrict__ hcat, const f16* __restrict__ W3p,
    const float* __restrict__ out_b, float* __restrict__ out) {
    const int mt0  = blockIdx.x << 2;
    const int wave = threadIdx.x >> 6;
    const int lane = threadIdx.x & 63;
    const int l16  = lane & 15;
    const int quad = lane >> 4;
    const int n0   = wave * 64;

    float bias_l[4];
#pragma unroll
    for (int nt = 0; nt < 4; ++nt) bias_l[nt] = out_b[n0 + nt * 16 + l16];

    f32x4 acc[4][4];
#pragma unroll
    for (int m = 0; m < 4; ++m)
#pragma unroll
        for (int nt = 0; nt < 4; ++nt)
#pragma unroll
            for (int q = 0; q < 4; ++q) acc[m][nt][q] = bias_l[nt];

#pragma unroll 2
    for (int kc = 0; kc < 16; ++kc) {
        f16x8 a[4], b[4];
#pragma unroll
        for (int m = 0; m < 4; ++m)
            a[m] = *(const f16x8*)(hcat + ((size_t)((mt0 + m) * 16 + kc) * 512 + lane * 8));
#pragma unroll
        for (int nt = 0; nt < 4; ++nt)
            b[nt] = *(const f16x8*)(W3p + ((kc * 32 + wave * 4 + nt) * 512 + lane * 8));
#pragma unroll
        for (int m = 0; m < 4; ++m)
#pragma unroll
            for (int nt = 0; nt < 4; ++nt)
                acc[m][nt] = MF(a[m], b[nt], acc[m][nt]);
    }

#pragma unroll
    for (int m = 0; m < 4; ++m) {
#pragma unroll
        for (int nt = 0; nt < 4; ++nt) {
#pragma unroll
            for (int q = 0; q < 4; ++q) {
                int R = mt0 * 16 + m * 16 + quad * 4 + q;
                int t = R >> 13;
                int b = R & 8191;
                out[(size_t)(b * 10 + t) * 512 + n0 + nt * 16 + l16] = acc[m][nt][q];
            }
        }
    }
}

// ---------------------------------------------------------------------------
extern "C" void kernel_launch(void* const* d_in, const int* in_sizes, int n_in,
                              void* d_out, int out_size, void* d_ws, size_t ws_size,
                              hipStream_t stream) {
    const int*   words   = (const int*)d_in[0];
    const int*   lengths = (const int*)d_in[1];
    const float* tab     = (const float*)d_in[2];
    const float* enc_w   = (const float*)d_in[3];
    const float* enc_b   = (const float*)d_in[4];
    const float* wih_f   = (const float*)d_in[5];
    const float* whh_f   = (const float*)d_in[6];
    const float* bih_f   = (const float*)d_in[7];
    const float* bhh_f   = (const float*)d_in[8];
    const float* wih_b   = (const float*)d_in[9];
    const float* whh_b   = (const float*)d_in[10];
    const float* bih_b   = (const float*)d_in[11];
    const float* bhh_b   = (const float*)d_in[12];
    const float* out_w   = (const float*)d_in[13];
    const float* out_b   = (const float*)d_in[14];
    float* out = (float*)d_out;

    char* ws = (char*)d_ws;
    f16*   Wp   = (f16*)(ws + 0);           //  2 MB
    f16*   W3p  = (f16*)(ws + 2097152);     //  0.5 MB
    float* bp   = (float*)(ws + 2621440);   //  8 KB
    float* P    = (float*)(ws + 2629632);   //  36 KB
    f16*   seqp = (f16*)(ws + 2666496);     //  40 MB
    f16*   hcat = (f16*)(ws + 44609536);    //  80 MB  (total ~122.6 MB)

    pack_w2<<<4096, 256, 0, stream>>>(wih_f, whh_f, wih_b, whh_b, Wp);
    pack_bias<<<8, 256, 0, stream>>>(bih_f, bhh_f, bih_b, bhh_b, bp);
    pack_w3<<<1024, 256, 0, stream>>>(out_w, W3p);
    enc_proj<<<36, 256, 0, stream>>>(tab, enc_w, enc_b, P);
    build_seq<<<10240, 256, 0, stream>>>(words, lengths, P, seqp);
    lstm_fused<<<256, 512, 0, stream>>>(seqp, Wp, bp, hcat);
    out_gemm<<<1280, 512, 0, stream>>>(hcat, W3p, out_b, out);
}